// Round 8
// baseline (505.390 us; speedup 1.0000x reference)
//
#include <hip/hip_runtime.h>
#include <hip/hip_bf16.h>
#include <stdint.h>

typedef __attribute__((ext_vector_type(8))) short bv8;   // 8 x bf16 (MFMA A/B frag)
typedef __attribute__((ext_vector_type(4))) short sv4;   // 4 x bf16
typedef __attribute__((ext_vector_type(4))) float f4;    // MFMA C/D frag
typedef __attribute__((ext_vector_type(4))) unsigned uv4;

#define LDS_AS __attribute__((address_space(3)))
#define GLB_AS __attribute__((address_space(1)))

#if __has_builtin(__builtin_amdgcn_exp2f)
#define EXP2F(x) __builtin_amdgcn_exp2f(x)
#else
#define EXP2F(x) exp2f(x)
#endif

__device__ __forceinline__ void gload16(const void* g, void* l) {
  // async global->LDS, 16B per lane; LDS dest is wave-uniform base + lane*16
  __builtin_amdgcn_global_load_lds((GLB_AS void*)(g), (LDS_AS void*)(l), 16, 0, 0);
}

__device__ __forceinline__ short f2bs(float x) {
  return __builtin_bit_cast(short, __float2bfloat16(x));
}
__device__ __forceinline__ float bs2f(short s) {
  unsigned u = ((unsigned)(unsigned short)s) << 16;
  return __builtin_bit_cast(float, u);
}
__device__ __forceinline__ unsigned cvtpk(float lo, float hi) {
  unsigned r;
  asm("v_cvt_pk_bf16_f32 %0, %1, %2" : "=v"(r) : "v"(lo), "v"(hi));
  return r;
}

// ---------------- fp32 -> bf16 convert (x) ----------------
__global__ __launch_bounds__(256) void k_cvt(const float* __restrict__ in, short* __restrict__ out) {
  const int i = (blockIdx.x * 256 + threadIdx.x) * 4;
  const float4 v = *(const float4*)(in + i);
  sv4 o; o[0] = f2bs(v.x); o[1] = f2bs(v.y); o[2] = f2bs(v.z); o[3] = f2bs(v.w);
  *(sv4*)(out + i) = o;
}

// ---------------- W [K][N] fp32 -> Wt [N][K] bf16 ----------------
__global__ __launch_bounds__(256) void k_transpose(const float* __restrict__ W, short* __restrict__ Wt,
                                                   int K, int N) {
  __shared__ float tile[32][33];
  const int tx = threadIdx.x & 31, ty = threadIdx.x >> 5;
  const int n0 = blockIdx.x * 32, k0 = blockIdx.y * 32;
#pragma unroll
  for (int i = 0; i < 32; i += 8)
    tile[ty + i][tx] = W[(size_t)(k0 + ty + i) * N + n0 + tx];
  __syncthreads();
#pragma unroll
  for (int i = 0; i < 32; i += 8)
    Wt[(size_t)(n0 + ty + i) * K + k0 + tx] = f2bs(tile[tx][ty + i]);
}

// ======== 256x128 GEMM, 3-buf LDS, 2-tile-deep prefetch, counted vmcnt (T3+T4) ========
// C[M][N] = A[M][K] @ Bt[N][K]^T + bias. 512 thr / 8 waves, per-wave 64x64 output.
// Invariant at tile t start (post-barrier): buf[t%3] staged; t+1's 6 loads/thread in
// flight; t+2 unissued. Tile end waits vmcnt(6) (t+1 landed, t+2 stays in flight) --
// the staging queue is NEVER drained to 0 in the main loop (this is what the m97
// structure's __syncthreads drain costs ~20%).
// EPI: 0 plain bf16 out, 1 relu bf16 out, 2 QKV scatter (C=Q, D2=K, D3=Vt).
template<int EPI>
__global__ __launch_bounds__(512) void k_gemm256(const short* __restrict__ A, const short* __restrict__ Bt,
                                                 const float* __restrict__ bias, const float* __restrict__ bias2,
                                                 const float* __restrict__ bias3,
                                                 short* __restrict__ C, short* __restrict__ D2,
                                                 short* __restrict__ D3,
                                                 int M, int N, int K, int nbx) {
  __shared__ __align__(16) short As[3][256 * 64];  // 96KB
  __shared__ __align__(16) short Bs[3][128 * 64];  // 48KB  (total 144KB, 1 block/CU)

  const int t = threadIdx.x;
  const int lane = t & 63, w = t >> 6;
  const int wm = w >> 1, wn = w & 1;           // 4 x 2 wave grid
  const int lr = lane & 15, lg = lane >> 4;
  // XCD swizzle (grid % 8 == 0 for all our shapes)
  const int nwg = gridDim.x, cpx = nwg >> 3;
  const int bid = blockIdx.x;
  const int wid = (bid & 7) * cpx + (bid >> 3);
  const int by = wid / nbx, bx = wid % nbx;
  const int m0 = by * 256, n0 = bx * 128;
  const int nt = K >> 6;

  auto STAGE = [&](int k0, int bufi) {
    char* ad = (char*)As[bufi];
    char* bd = (char*)Bs[bufi];
#pragma unroll
    for (int i = 0; i < 4; ++i) {
      const int L = t * 16 + i * 8192;
      const int row = L >> 7;
      const int cbs = (L & 127) ^ ((row & 7) << 4);
      gload16(A + (size_t)(m0 + row) * K + k0 + (cbs >> 1), ad + L);
    }
#pragma unroll
    for (int i = 0; i < 2; ++i) {
      const int L = t * 16 + i * 8192;
      const int row = L >> 7;
      const int cbs = (L & 127) ^ ((row & 7) << 4);
      gload16(Bt + (size_t)(n0 + row) * K + k0 + (cbs >> 1), bd + L);
    }
  };

  f4 acc[4][4] = {};

  // prologue: stage tiles 0 and 1; wait for tile 0 only (vmcnt(6) leaves t1 in flight)
  STAGE(0, 0);
  STAGE(64, 1);
  asm volatile("s_waitcnt vmcnt(6)" ::: "memory");
  __builtin_amdgcn_sched_barrier(0);
  __builtin_amdgcn_s_barrier();
  __builtin_amdgcn_sched_barrier(0);

  int cur = 0;
  for (int tt = 0; tt < nt; ++tt) {
    // issue stage of tile tt+2 into the buffer being freed this iteration
    if (tt + 2 < nt) {
      int b2 = cur + 2; if (b2 >= 3) b2 -= 3;
      STAGE((tt + 2) << 6, b2);
    }
    const char* Ab = (const char*)As[cur];
    const char* Bb = (const char*)Bs[cur];
#pragma unroll
    for (int kk = 0; kk < 2; ++kk) {
      bv8 af[4], bf[4];
#pragma unroll
      for (int mi = 0; mi < 4; ++mi) {
        const int row = wm * 64 + mi * 16 + lr;
        const int cb = kk * 64 + lg * 16;
        af[mi] = *(const bv8*)(Ab + row * 128 + (cb ^ ((row & 7) << 4)));
      }
#pragma unroll
      for (int ni = 0; ni < 4; ++ni) {
        const int row = wn * 64 + ni * 16 + lr;
        const int cb = kk * 64 + lg * 16;
        bf[ni] = *(const bv8*)(Bb + row * 128 + (cb ^ ((row & 7) << 4)));
      }
      __builtin_amdgcn_s_setprio(1);
#pragma unroll
      for (int mi = 0; mi < 4; ++mi)
#pragma unroll
        for (int ni = 0; ni < 4; ++ni)
          acc[mi][ni] = __builtin_amdgcn_mfma_f32_16x16x32_bf16(af[mi], bf[ni], acc[mi][ni], 0, 0, 0);
      __builtin_amdgcn_s_setprio(0);
    }
    // end-of-tile sync: wait ONLY for tile tt+1's loads (tt+2's stay in flight)
    if (tt + 1 < nt) {
      if (tt + 2 < nt) asm volatile("s_waitcnt vmcnt(6)" ::: "memory");
      else             asm volatile("s_waitcnt vmcnt(0)" ::: "memory");
      __builtin_amdgcn_sched_barrier(0);
      __builtin_amdgcn_s_barrier();
      __builtin_amdgcn_sched_barrier(0);
    }
    cur += 1; if (cur >= 3) cur -= 3;
  }

  // epilogue
#pragma unroll
  for (int ni = 0; ni < 4; ++ni) {
    const int c = n0 + wn * 64 + ni * 16 + lr;
    float bvs;
    int sel = 0, cc = c, h = 0, d = 0;
    if (EPI == 2) {
      sel = c >> 10; cc = c & 1023;
      bvs = (sel == 0 ? bias : sel == 1 ? bias2 : bias3)[cc];
      h = cc >> 6; d = cc & 63;
    } else {
      bvs = bias[c];
    }
#pragma unroll
    for (int mi = 0; mi < 4; ++mi) {
#pragma unroll
      for (int j = 0; j < 4; ++j) {
        const int r = m0 + wm * 64 + mi * 16 + lg * 4 + j;  // C/D: col=lane&15, row=(lane>>4)*4+reg
        float v = acc[mi][ni][j] + bvs;
        if (EPI == 1) v = fmaxf(v, 0.f);
        if (EPI == 2) {
          const int bb = r >> 11, s = r & 2047;
          if (sel == 0)      C [((size_t)(bb * 16 + h) * 2048 + s) * 64 + d] = f2bs(v);
          else if (sel == 1) D2[((size_t)(bb * 16 + h) * 2048 + s) * 64 + d] = f2bs(v);
          else               D3[((size_t)(bb * 16 + h) * 64 + d) * 2048 + s] = f2bs(v);
        } else {
          C[(size_t)r * N + c] = f2bs(v);
        }
      }
    }
  }
}

// ---------------- flash attention (R6 best: 4 waves, in-register P, 176us) ----------------
// per block = (q-tile 128, bh), 4 waves x 32 q-rows. S^T = mfma(K,Q): q on lane&15,
// k on reg axis -> lane-local softmax. P->PV B-frag redistribution IN REGISTERS:
// cvt_pk pairs + shfl_xor(32)/shfl_xor(16) 4-group exchange. Fixed-max softmax.
// K tile dbuf in LDS (32KB), stage-ahead; single barrier per tile.
__global__ __launch_bounds__(256) void k_attn(const short* __restrict__ Qg, const short* __restrict__ Kg,
                                              const short* __restrict__ Vtg, short* __restrict__ Oc) {
  __shared__ __align__(16) short Ks[2][128 * 64];  // dbuf [s][dk] swizzled, 128B rows

  const int t = threadIdx.x, lane = t & 63, w = t >> 6;
  const int lr = lane & 15, lg = lane >> 4;
  const int bid = blockIdx.x;
  const int wid = (bid & 7) * 128 + (bid >> 3);
  const int q0 = (wid & 15) * 128;
  const int bh = wid >> 4;
  const int b = bh >> 4, h = bh & 15;
  const short* Qp = Qg + (size_t)bh * 2048 * 64;
  const short* Kp = Kg + (size_t)bh * 2048 * 64;
  const short* Vp = Vtg + (size_t)bh * 64 * 2048;

  bv8 qf[2][2];
#pragma unroll
  for (int mi = 0; mi < 2; ++mi)
#pragma unroll
    for (int kk = 0; kk < 2; ++kk)
      qf[mi][kk] = *(const bv8*)(Qp + (size_t)(q0 + w * 32 + mi * 16 + lr) * 64 + kk * 32 + lg * 8);

  f4 Oa[2][4] = {};
  float lsum[2] = {0.f, 0.f};
  const float SC = 0.125f * 1.44269504089f;
  const bool hi = lg >= 2;
  const bool xx = (lg == 1) || (lg == 2);

#pragma unroll
  for (int i = 0; i < 4; ++i) {
    const int L = t * 16 + i * 4096;
    const int row = L >> 7;
    const int cbs = (L & 127) ^ ((row & 7) << 4);
    gload16(Kp + (size_t)row * 64 + (cbs >> 1), (char*)Ks[0] + L);
  }
  __syncthreads();

  int cur = 0;
  for (int kt = 0; kt < 2048; kt += 128) {
    if (kt + 128 < 2048) {
#pragma unroll
      for (int i = 0; i < 4; ++i) {
        const int L = t * 16 + i * 4096;
        const int row = L >> 7;
        const int cbs = (L & 127) ^ ((row & 7) << 4);
        gload16(Kp + (size_t)(kt + 128 + row) * 64 + (cbs >> 1), (char*)Ks[cur ^ 1] + L);
      }
    }
    const char* Kb = (const char*)Ks[cur];

#pragma unroll
    for (int hf = 0; hf < 2; ++hf) {
      f4 Sa[2][4] = {};
#pragma unroll
      for (int kk = 0; kk < 2; ++kk) {
        bv8 kf[4];
#pragma unroll
        for (int nl = 0; nl < 4; ++nl) {
          const int row = (hf * 4 + nl) * 16 + lr;
          const int cb = kk * 64 + lg * 16;
          kf[nl] = *(const bv8*)(Kb + row * 128 + (cb ^ ((row & 7) << 4)));
        }
        __builtin_amdgcn_s_setprio(1);
#pragma unroll
        for (int mi = 0; mi < 2; ++mi)
#pragma unroll
          for (int nl = 0; nl < 4; ++nl)
            Sa[mi][nl] = __builtin_amdgcn_mfma_f32_16x16x32_bf16(kf[nl], qf[mi][kk], Sa[mi][nl], 0, 0, 0);
        __builtin_amdgcn_s_setprio(0);
      }

#pragma unroll
      for (int mi = 0; mi < 2; ++mi) {
        float rs = 0.f;
#pragma unroll
        for (int nl = 0; nl < 4; ++nl)
#pragma unroll
          for (int j = 0; j < 4; ++j) {
            const float p = EXP2F(Sa[mi][nl][j] * SC);
            Sa[mi][nl][j] = p;
            rs += p;
          }
        lsum[mi] += rs;
      }

#pragma unroll
      for (int k2 = 0; k2 < 2; ++k2) {
        bv8 vf[4], pf[2];
#pragma unroll
        for (int nO = 0; nO < 4; ++nO)
          vf[nO] = *(const bv8*)(Vp + (size_t)(nO * 16 + lr) * 2048 + kt + hf * 64 + k2 * 32 + lg * 8);
#pragma unroll
        for (int mi = 0; mi < 2; ++mi) {
          const unsigned W0 = cvtpk(Sa[mi][2 * k2][0], Sa[mi][2 * k2][1]);
          const unsigned W1 = cvtpk(Sa[mi][2 * k2][2], Sa[mi][2 * k2][3]);
          const unsigned W2 = cvtpk(Sa[mi][2 * k2 + 1][0], Sa[mi][2 * k2 + 1][1]);
          const unsigned W3 = cvtpk(Sa[mi][2 * k2 + 1][2], Sa[mi][2 * k2 + 1][3]);
          const unsigned w0 = hi ? W2 : W0, w1 = hi ? W3 : W1;
          const unsigned s0 = __shfl_xor(hi ? W0 : W2, 32);
          const unsigned s1 = __shfl_xor(hi ? W1 : W3, 32);
          const unsigned t0 = __shfl_xor(xx ? w0 : s0, 16);
          const unsigned t1 = __shfl_xor(xx ? w1 : s1, 16);
          uv4 u;
          u[0] = (lg == 0) ? w0 : (lg == 2) ? s0 : t0;
          u[1] = (lg == 0) ? w1 : (lg == 2) ? s1 : t1;
          u[2] = (lg == 3) ? w0 : (lg == 1) ? s0 : t0;
          u[3] = (lg == 3) ? w1 : (lg == 1) ? s1 : t1;
          pf[mi] = __builtin_bit_cast(bv8, u);
        }
        __builtin_amdgcn_s_setprio(1);
#pragma unroll
        for (int mi = 0; mi < 2; ++mi)
#pragma unroll
          for (int nO = 0; nO < 4; ++nO)
            Oa[mi][nO] = __builtin_amdgcn_mfma_f32_16x16x32_bf16(vf[nO], pf[mi], Oa[mi][nO], 0, 0, 0);
        __builtin_amdgcn_s_setprio(0);
      }
    }

    __syncthreads();
    cur ^= 1;
  }

#pragma unroll
  for (int mi = 0; mi < 2; ++mi) {
    lsum[mi] += __shfl_xor(lsum[mi], 16);
    lsum[mi] += __shfl_xor(lsum[mi], 32);
  }

#pragma unroll
  for (int mi = 0; mi < 2; ++mi) {
    const float inv = 1.f / lsum[mi];
    const int q = q0 + w * 32 + mi * 16 + lr;
#pragma unroll
    for (int nO = 0; nO < 4; ++nO) {
      sv4 o;
#pragma unroll
      for (int j = 0; j < 4; ++j) o[j] = f2bs(Oa[mi][nO][j] * inv);
      const int c = h * 64 + nO * 16 + lg * 4;
      *(sv4*)(Oc + ((size_t)b * 2048 + q) * 1024 + c) = o;
    }
  }
}

// ---------------- residual + LayerNorm (mean, unbiased std, eps on std) ----------------
// MODE 0: residual fp32, out bf16.  MODE 1: residual bf16, out fp32.
template<int MODE>
__global__ __launch_bounds__(256) void k_resnorm(const short* __restrict__ a, const void* __restrict__ res,
                                                 const float* __restrict__ alpha, const float* __restrict__ beta,
                                                 void* __restrict__ out) {
  const int row = blockIdx.x;
  const int t = threadIdx.x;
  const int lane = t & 63, w = t >> 6;
  const size_t base = (size_t)row * 1024;

  const sv4 av = *(const sv4*)(a + base + t * 4);
  float v[4];
  if (MODE == 0) {
    const float4 rv = *(const float4*)((const float*)res + base + t * 4);
    v[0] = bs2f(av[0]) + rv.x; v[1] = bs2f(av[1]) + rv.y;
    v[2] = bs2f(av[2]) + rv.z; v[3] = bs2f(av[3]) + rv.w;
  } else {
    const sv4 rv = *(const sv4*)((const short*)res + base + t * 4);
#pragma unroll
    for (int i = 0; i < 4; ++i) v[i] = bs2f(av[i]) + bs2f(rv[i]);
  }
  float s = v[0] + v[1] + v[2] + v[3];
  float sq = v[0] * v[0] + v[1] * v[1] + v[2] * v[2] + v[3] * v[3];
#pragma unroll
  for (int m = 1; m < 64; m <<= 1) { s += __shfl_xor(s, m); sq += __shfl_xor(sq, m); }
  __shared__ float red[8];
  if (lane == 0) { red[w] = s; red[w + 4] = sq; }
  __syncthreads();
  s = red[0] + red[1] + red[2] + red[3];
  sq = red[4] + red[5] + red[6] + red[7];
  const float mean = s * (1.f / 1024.f);
  const float var = (sq - 1024.f * mean * mean) * (1.f / 1023.f);   // ddof=1
  const float inv = 1.f / (sqrtf(fmaxf(var, 0.f)) + 1e-6f);          // eps added to std
  const float4 al = *(const float4*)(alpha + t * 4);
  const float4 be = *(const float4*)(beta + t * 4);
  float y[4];
  y[0] = al.x * (v[0] - mean) * inv + be.x;
  y[1] = al.y * (v[1] - mean) * inv + be.y;
  y[2] = al.z * (v[2] - mean) * inv + be.z;
  y[3] = al.w * (v[3] - mean) * inv + be.w;
  if (MODE == 0) {
    sv4 o; o[0] = f2bs(y[0]); o[1] = f2bs(y[1]); o[2] = f2bs(y[2]); o[3] = f2bs(y[3]);
    *(sv4*)((short*)out + base + t * 4) = o;
  } else {
    *(float4*)((float*)out + base + t * 4) = make_float4(y[0], y[1], y[2], y[3]);
  }
}

extern "C" void kernel_launch(void* const* d_in, const int* in_sizes, int n_in,
                              void* d_out, int out_size, void* d_ws, size_t ws_size,
                              hipStream_t stream) {
  const float* x   = (const float*)d_in[0];
  const float* Wq  = (const float*)d_in[1];
  const float* bq  = (const float*)d_in[2];
  const float* Wk  = (const float*)d_in[3];
  const float* bk  = (const float*)d_in[4];
  const float* Wv  = (const float*)d_in[5];
  const float* bv  = (const float*)d_in[6];
  const float* Wo  = (const float*)d_in[7];
  const float* bo  = (const float*)d_in[8];
  const float* al1 = (const float*)d_in[9];
  const float* bi1 = (const float*)d_in[10];
  const float* al2 = (const float*)d_in[11];
  const float* bi2 = (const float*)d_in[12];
  const float* W1  = (const float*)d_in[13];
  const float* b1  = (const float*)d_in[14];
  const float* W2  = (const float*)d_in[15];
  const float* b2  = (const float*)d_in[16];

  if (ws_size < (size_t)136 * 1024 * 1024) return;  // need 136MB scratch

  char* ws = (char*)d_ws;
  short* xb  = (short*)(ws);                   // 16MB, dead after QKV
  short* Qb  = (short*)(ws + (16ll << 20));    // 16MB
  short* Kb  = (short*)(ws + (32ll << 20));    // 16MB
  short* Vtb = (short*)(ws + (48ll << 20));    // 16MB
  short* Hb  = (short*)(ws);                   // 64MB: reuses xb+Q+K+Vt after attention
  short* Wqt = (short*)(ws + (64ll << 20));    // [3072][1024] contiguous with Wkt/Wvt
  short* Wkt = (short*)(ws + (66ll << 20));
  short* Wvt = (short*)(ws + (68ll << 20));
  short* Wot = (short*)(ws + (70ll << 20));
  short* W1t = (short*)(ws + (72ll << 20));    // 8MB
  short* W2t = (short*)(ws + (80ll << 20));    // 8MB
  short* Cc  = (short*)(ws + (88ll << 20));    // 16MB
  short* AOb = (short*)(ws + (104ll << 20));   // 16MB, reused for FFb
  short* N1b = (short*)(ws + (120ll << 20));   // 16MB
  short* FFb = (short*)(ws + (104ll << 20));

  // prep: bf16 conversions + weight transposes
  k_cvt<<<8192, 256, 0, stream>>>(x, xb);
  k_transpose<<<dim3(32, 32), 256, 0, stream>>>(Wq, Wqt, 1024, 1024);
  k_transpose<<<dim3(32, 32), 256, 0, stream>>>(Wk, Wkt, 1024, 1024);
  k_transpose<<<dim3(32, 32), 256, 0, stream>>>(Wv, Wvt, 1024, 1024);
  k_transpose<<<dim3(32, 32), 256, 0, stream>>>(Wo, Wot, 1024, 1024);
  k_transpose<<<dim3(128, 32), 256, 0, stream>>>(W1, W1t, 1024, 4096);
  k_transpose<<<dim3(32, 128), 256, 0, stream>>>(W2, W2t, 4096, 1024);

  // fused QKV projection: 8192x3072 @ K=1024, grid (8192/256)*(3072/128) = 32*24 = 768
  k_gemm256<2><<<768, 512, 0, stream>>>(xb, Wqt, bq, bk, bv, Qb, Kb, Vtb, 8192, 3072, 1024, 24);

  // attention -> concat (1D grid for XCD swizzle)
  k_attn<<<1024, 256, 0, stream>>>(Qb, Kb, Vtb, Cc);

  // output proj + LN1: 8192x1024 @ K=1024, grid 32*8 = 256
  k_gemm256<0><<<256, 512, 0, stream>>>(Cc, Wot, bo, nullptr, nullptr, AOb, nullptr, nullptr,
                                        8192, 1024, 1024, 8);
  k_resnorm<0><<<8192, 256, 0, stream>>>(AOb, x, al1, bi1, N1b);

  // FFN1: 8192x4096 @ K=1024 relu, grid 32*32 = 1024
  k_gemm256<1><<<1024, 512, 0, stream>>>(N1b, W1t, b1, nullptr, nullptr, Hb, nullptr, nullptr,
                                         8192, 4096, 1024, 32);
  // FFN2: 8192x1024 @ K=4096, grid 32*8 = 256
  k_gemm256<0><<<256, 512, 0, stream>>>(Hb, W2t, b2, nullptr, nullptr, FFb, nullptr, nullptr,
                                        8192, 1024, 4096, 8);
  k_resnorm<1><<<8192, 256, 0, stream>>>(FFb, N1b, al2, bi2, (float*)d_out);
}

// Round 9
// 473.863 us; speedup vs baseline: 1.0665x; 1.0665x over previous
//
#include <hip/hip_runtime.h>
#include <hip/hip_bf16.h>
#include <stdint.h>

typedef __attribute__((ext_vector_type(8))) short bv8;   // 8 x bf16 (MFMA A/B frag)
typedef __attribute__((ext_vector_type(4))) short sv4;   // 4 x bf16
typedef __attribute__((ext_vector_type(4))) float f4;    // MFMA C/D frag
typedef __attribute__((ext_vector_type(4))) unsigned uv4;

#define LDS_AS __attribute__((address_space(3)))
#define GLB_AS __attribute__((address_space(1)))

#if __has_builtin(__builtin_amdgcn_exp2f)
#define EXP2F(x) __builtin_amdgcn_exp2f(x)
#else
#define EXP2F(x) exp2f(x)
#endif

#define GBAR __builtin_amdgcn_s_barrier()

__device__ __forceinline__ void gload16(const void* g, void* l) {
  __builtin_amdgcn_global_load_lds((GLB_AS void*)(g), (LDS_AS void*)(l), 16, 0, 0);
}

__device__ __forceinline__ short f2bs(float x) {
  return __builtin_bit_cast(short, __float2bfloat16(x));
}
__device__ __forceinline__ float bs2f(short s) {
  unsigned u = ((unsigned)(unsigned short)s) << 16;
  return __builtin_bit_cast(float, u);
}
__device__ __forceinline__ unsigned cvtpk(float lo, float hi) {
  unsigned r;
  asm("v_cvt_pk_bf16_f32 %0, %1, %2" : "=v"(r) : "v"(lo), "v"(hi));
  return r;
}

// ---------------- fp32 -> bf16 convert (x) ----------------
__global__ __launch_bounds__(256) void k_cvt(const float* __restrict__ in, short* __restrict__ out) {
  const int i = (blockIdx.x * 256 + threadIdx.x) * 4;
  const float4 v = *(const float4*)(in + i);
  sv4 o; o[0] = f2bs(v.x); o[1] = f2bs(v.y); o[2] = f2bs(v.z); o[3] = f2bs(v.w);
  *(sv4*)(out + i) = o;
}

// ---------------- W [K][N] fp32 -> Wt [N][K] bf16 ----------------
__global__ __launch_bounds__(256) void k_transpose(const float* __restrict__ W, short* __restrict__ Wt,
                                                   int K, int N) {
  __shared__ float tile[32][33];
  const int tx = threadIdx.x & 31, ty = threadIdx.x >> 5;
  const int n0 = blockIdx.x * 32, k0 = blockIdx.y * 32;
#pragma unroll
  for (int i = 0; i < 32; i += 8)
    tile[ty + i][tx] = W[(size_t)(k0 + ty + i) * N + n0 + tx];
  __syncthreads();
#pragma unroll
  for (int i = 0; i < 32; i += 8)
    Wt[(size_t)(n0 + ty + i) * K + k0 + tx] = f2bs(tile[tx][ty + i]);
}

// ======== 8-phase GEMM (T2+T3+T4+T5): BMxBN tile, BN=256, BM=MIH*64 ========
// C[M][N] = A[M][K] @ Bt[N][K]^T + bias. 512 thr / 8 waves (2M x 4N).
// Per iteration: 2 K-tiles (buf0=even, buf1=odd; FIXED roles), 8 phases, each:
//   {ds_read quadrant frags || issue 1 slab stage} -> s_barrier ->
//   setprio(1) + MFMA quadrant + setprio(0) -> s_barrier
// Snake quadrants Q(lo,lo),Q(lo,hi),Q(hi,hi),Q(hi,lo) => slab death order
// A-lo,B-hi,A-hi,B-lo; each phase stages the slab that died the previous phase,
// 2 tiles ahead. vmcnt counted (6 for MIH4 / 4 for MIH2) at phases 4,8 ONLY;
// loads are never drained in the main loop. Tail iterations fall back to vmcnt(0).
// EPI: 0 plain bf16, 1 relu bf16, 2 QKV scatter (C=Q, D2=K, D3=Vt).
template<int EPI, int MIH>
__global__ __launch_bounds__(512) void k_gemm8p(
    const short* __restrict__ A, const short* __restrict__ Bt,
    const float* __restrict__ bias, const float* __restrict__ bias2, const float* __restrict__ bias3,
    short* __restrict__ C, short* __restrict__ D2, short* __restrict__ D3,
    int M, int N, int K, int nbx) {
  constexpr int BM = MIH * 64;
  constexpr int HOFF = (MIH == 4) ? 16384 : 4096;   // A half-slab byte offset
  __shared__ __align__(16) short SA[2][BM * 64];    // 2 x (BM x 64) bf16
  __shared__ __align__(16) short SB[2][256 * 64];   // 2 x (256 x 64) bf16

  const int t = threadIdx.x;
  const int lane = t & 63, w = t >> 6;
  const int wr = w >> 2, wc = w & 3;
  const int lr = lane & 15, lg = lane >> 4;
  const int cpx = gridDim.x >> 3;
  const int bid = blockIdx.x;
  const int wid = (bid & 7) * cpx + (bid >> 3);     // XCD swizzle (grid % 8 == 0)
  const int by = wid / nbx, bx = wid % nbx;
  const int m0 = by * BM, n0 = bx * 256;
  const int nt = K >> 6;
  const int swz = ((t >> 3) & 7) << 4;
  const int rbyte0 = (lg * 16) ^ ((lr & 7) << 4);
  const int rbyte1 = (64 + lg * 16) ^ ((lr & 7) << 4);

  auto ST_A = [&](int k0, int half, int buf) {      // 16KB slab = 2 gload16/thread
#pragma unroll
    for (int i = 0; i < 2; ++i) {
      const int L = t * 16 + i * 8192;
      const int cbs = (L & 127) ^ swz;
      const int grow = (MIH == 4) ? (m0 + i * 128 + half * 64 + (t >> 3))
                                  : (m0 + i * 64 + (t >> 3));
      gload16(A + (size_t)grow * K + k0 + (cbs >> 1),
              (char*)SA[buf] + (MIH == 4 ? half * 16384 : 0) + L);
    }
  };
  auto ST_B = [&](int k0, int half, int buf) {
#pragma unroll
    for (int i = 0; i < 2; ++i) {
      const int L = t * 16 + i * 8192;
      const int rr = (t >> 3) + i * 64;
      const int cbs = (L & 127) ^ swz;
      const int grow = n0 + (rr >> 5) * 64 + half * 32 + (rr & 31);
      gload16(Bt + (size_t)grow * K + k0 + (cbs >> 1),
              (char*)SB[buf] + half * 16384 + L);
    }
  };

  f4 acc[2 * MIH][4] = {};
  bv8 af[MIH][2], bflo[2][2], bfhi[2][2];

  auto LDA = [&](int buf, int half) {
    const char* base = (const char*)SA[buf] + half * HOFF + wr * 8192;
#pragma unroll
    for (int m = 0; m < MIH; ++m) {
      af[m][0] = *(const bv8*)(base + (m * 16 + lr) * 128 + rbyte0);
      af[m][1] = *(const bv8*)(base + (m * 16 + lr) * 128 + rbyte1);
    }
  };
  auto LDB = [&](int buf, int half, bv8 (&bf)[2][2]) {
    const char* base = (const char*)SB[buf] + half * 16384 + wc * 4096;
#pragma unroll
    for (int n = 0; n < 2; ++n) {
      bf[n][0] = *(const bv8*)(base + (n * 16 + lr) * 128 + rbyte0);
      bf[n][1] = *(const bv8*)(base + (n * 16 + lr) * 128 + rbyte1);
    }
  };
  auto MM = [&](bv8 (&bf)[2][2], int mB, int nB) {
    __builtin_amdgcn_s_setprio(1);
#pragma unroll
    for (int kk = 0; kk < 2; ++kk)
#pragma unroll
      for (int m = 0; m < MIH; ++m)
#pragma unroll
        for (int n = 0; n < 2; ++n)
          acc[mB + m][nB + n] = __builtin_amdgcn_mfma_f32_16x16x32_bf16(
              af[m][kk], bf[n][kk], acc[mB + m][nB + n], 0, 0, 0);
    __builtin_amdgcn_s_setprio(0);
  };

  // prologue: tile0 complete; tile1 all but B-slab0 (staged at P1 of iter 0)
  ST_A(0, 0, 0); if (MIH == 4) ST_A(0, 1, 0);
  ST_B(0, 0, 0); ST_B(0, 1, 0);
  ST_A(64, 0, 1);
  ST_B(64, 1, 1);
  if (MIH == 4) { ST_A(64, 1, 1); asm volatile("s_waitcnt vmcnt(6)" ::: "memory"); }
  else          { asm volatile("s_waitcnt vmcnt(4)" ::: "memory"); }
  GBAR;

  const int nIter = nt >> 1;
  for (int it = 0; it < nIter; ++it) {
    const int k1 = (2 * it + 1) << 6;
    const int k2 = (2 * it + 2) << 6, k3 = (2 * it + 3) << 6;
    const bool h2 = (2 * it + 2) < nt, h3 = (2 * it + 3) < nt;

    // ---- even tile (buf0) ----
    // P1: Q(lo,lo); stage B-slab0 of odd tile (buf1)
    LDA(0, 0); LDB(0, 0, bflo);
    ST_B(k1, 0, 1);
    GBAR; MM(bflo, 0, 0); GBAR;
    // P2: Q(lo,hi); stage A-slab0(t+2)
    LDB(0, 1, bfhi);
    if (h2 && MIH == 4) ST_A(k2, 0, 0);
    GBAR; MM(bfhi, 0, 2); GBAR;
    // P3: Q(hi,hi); stage B-slab1(t+2)
    LDA(0, 1);
    if (h2) ST_B(k2, 1, 0);
    GBAR; MM(bfhi, MIH, 2); GBAR;
    // P4: Q(hi,lo); stage A-slab1(t+2); counted vmcnt
    if (h2) ST_A(k2, (MIH == 4) ? 1 : 0, 0);
    if (h2) {
      if (MIH == 4) asm volatile("s_waitcnt vmcnt(6)" ::: "memory");
      else          asm volatile("s_waitcnt vmcnt(4)" ::: "memory");
    } else {
      asm volatile("s_waitcnt vmcnt(0)" ::: "memory");
    }
    GBAR; MM(bflo, MIH, 0); GBAR;

    // ---- odd tile (buf1) ----
    // P5
    LDA(1, 0); LDB(1, 0, bflo);
    if (h2) ST_B(k2, 0, 0);
    GBAR; MM(bflo, 0, 0); GBAR;
    // P6
    LDB(1, 1, bfhi);
    if (h3 && MIH == 4) ST_A(k3, 0, 1);
    GBAR; MM(bfhi, 0, 2); GBAR;
    // P7
    LDA(1, 1);
    if (h3) ST_B(k3, 1, 1);
    GBAR; MM(bfhi, MIH, 2); GBAR;
    // P8
    if (h3) ST_A(k3, (MIH == 4) ? 1 : 0, 1);
    if (h3) {
      if (MIH == 4) asm volatile("s_waitcnt vmcnt(6)" ::: "memory");
      else          asm volatile("s_waitcnt vmcnt(4)" ::: "memory");
    } else {
      asm volatile("s_waitcnt vmcnt(0)" ::: "memory");
    }
    GBAR; MM(bflo, MIH, 0); GBAR;
  }

  // epilogue
#pragma unroll
  for (int ni = 0; ni < 4; ++ni) {
    const int c = n0 + wc * 64 + ni * 16 + lr;
    float bvs;
    int sel = 0, h = 0, d = 0;
    if (EPI == 2) {
      sel = c >> 10; const int cc = c & 1023;
      bvs = (sel == 0 ? bias : sel == 1 ? bias2 : bias3)[cc];
      h = cc >> 6; d = cc & 63;
    } else {
      bvs = bias[c];
    }
#pragma unroll
    for (int mi = 0; mi < 2 * MIH; ++mi) {
#pragma unroll
      for (int j = 0; j < 4; ++j) {
        const int r = m0 + wr * (MIH * 32) + mi * 16 + lg * 4 + j;
        float v = acc[mi][ni][j] + bvs;
        if (EPI == 1) v = fmaxf(v, 0.f);
        if (EPI == 2) {
          const int bb = r >> 11, s = r & 2047;
          if (sel == 0)      C [((size_t)(bb * 16 + h) * 2048 + s) * 64 + d] = f2bs(v);
          else if (sel == 1) D2[((size_t)(bb * 16 + h) * 2048 + s) * 64 + d] = f2bs(v);
          else               D3[((size_t)(bb * 16 + h) * 64 + d) * 2048 + s] = f2bs(v);
        } else {
          C[(size_t)r * N + c] = f2bs(v);
        }
      }
    }
  }
}

// ---------------- flash attention (R6 best: 4 waves, in-register P) ----------------
__global__ __launch_bounds__(256) void k_attn(const short* __restrict__ Qg, const short* __restrict__ Kg,
                                              const short* __restrict__ Vtg, short* __restrict__ Oc) {
  __shared__ __align__(16) short Ks[2][128 * 64];  // dbuf [s][dk] swizzled, 128B rows

  const int t = threadIdx.x, lane = t & 63, w = t >> 6;
  const int lr = lane & 15, lg = lane >> 4;
  const int bid = blockIdx.x;
  const int wid = (bid & 7) * 128 + (bid >> 3);
  const int q0 = (wid & 15) * 128;
  const int bh = wid >> 4;
  const int b = bh >> 4, h = bh & 15;
  const short* Qp = Qg + (size_t)bh * 2048 * 64;
  const short* Kp = Kg + (size_t)bh * 2048 * 64;
  const short* Vp = Vtg + (size_t)bh * 64 * 2048;

  bv8 qf[2][2];
#pragma unroll
  for (int mi = 0; mi < 2; ++mi)
#pragma unroll
    for (int kk = 0; kk < 2; ++kk)
      qf[mi][kk] = *(const bv8*)(Qp + (size_t)(q0 + w * 32 + mi * 16 + lr) * 64 + kk * 32 + lg * 8);

  f4 Oa[2][4] = {};
  float lsum[2] = {0.f, 0.f};
  const float SC = 0.125f * 1.44269504089f;
  const bool hi = lg >= 2;
  const bool xx = (lg == 1) || (lg == 2);

#pragma unroll
  for (int i = 0; i < 4; ++i) {
    const int L = t * 16 + i * 4096;
    const int row = L >> 7;
    const int cbs = (L & 127) ^ ((row & 7) << 4);
    gload16(Kp + (size_t)row * 64 + (cbs >> 1), (char*)Ks[0] + L);
  }
  __syncthreads();

  int cur = 0;
  for (int kt = 0; kt < 2048; kt += 128) {
    if (kt + 128 < 2048) {
#pragma unroll
      for (int i = 0; i < 4; ++i) {
        const int L = t * 16 + i * 4096;
        const int row = L >> 7;
        const int cbs = (L & 127) ^ ((row & 7) << 4);
        gload16(Kp + (size_t)(kt + 128 + row) * 64 + (cbs >> 1), (char*)Ks[cur ^ 1] + L);
      }
    }
    const char* Kb = (const char*)Ks[cur];

#pragma unroll
    for (int hf = 0; hf < 2; ++hf) {
      f4 Sa[2][4] = {};
#pragma unroll
      for (int kk = 0; kk < 2; ++kk) {
        bv8 kf[4];
#pragma unroll
        for (int nl = 0; nl < 4; ++nl) {
          const int row = (hf * 4 + nl) * 16 + lr;
          const int cb = kk * 64 + lg * 16;
          kf[nl] = *(const bv8*)(Kb + row * 128 + (cb ^ ((row & 7) << 4)));
        }
        __builtin_amdgcn_s_setprio(1);
#pragma unroll
        for (int mi = 0; mi < 2; ++mi)
#pragma unroll
          for (int nl = 0; nl < 4; ++nl)
            Sa[mi][nl] = __builtin_amdgcn_mfma_f32_16x16x32_bf16(kf[nl], qf[mi][kk], Sa[mi][nl], 0, 0, 0);
        __builtin_amdgcn_s_setprio(0);
      }

#pragma unroll
      for (int mi = 0; mi < 2; ++mi) {
        float rs = 0.f;
#pragma unroll
        for (int nl = 0; nl < 4; ++nl)
#pragma unroll
          for (int j = 0; j < 4; ++j) {
            const float p = EXP2F(Sa[mi][nl][j] * SC);
            Sa[mi][nl][j] = p;
            rs += p;
          }
        lsum[mi] += rs;
      }

#pragma unroll
      for (int k2 = 0; k2 < 2; ++k2) {
        bv8 vf[4], pf[2];
#pragma unroll
        for (int nO = 0; nO < 4; ++nO)
          vf[nO] = *(const bv8*)(Vp + (size_t)(nO * 16 + lr) * 2048 + kt + hf * 64 + k2 * 32 + lg * 8);
#pragma unroll
        for (int mi = 0; mi < 2; ++mi) {
          const unsigned W0 = cvtpk(Sa[mi][2 * k2][0], Sa[mi][2 * k2][1]);
          const unsigned W1 = cvtpk(Sa[mi][2 * k2][2], Sa[mi][2 * k2][3]);
          const unsigned W2 = cvtpk(Sa[mi][2 * k2 + 1][0], Sa[mi][2 * k2 + 1][1]);
          const unsigned W3 = cvtpk(Sa[mi][2 * k2 + 1][2], Sa[mi][2 * k2 + 1][3]);
          const unsigned w0 = hi ? W2 : W0, w1 = hi ? W3 : W1;
          const unsigned s0 = __shfl_xor(hi ? W0 : W2, 32);
          const unsigned s1 = __shfl_xor(hi ? W1 : W3, 32);
          const unsigned t0 = __shfl_xor(xx ? w0 : s0, 16);
          const unsigned t1 = __shfl_xor(xx ? w1 : s1, 16);
          uv4 u;
          u[0] = (lg == 0) ? w0 : (lg == 2) ? s0 : t0;
          u[1] = (lg == 0) ? w1 : (lg == 2) ? s1 : t1;
          u[2] = (lg == 3) ? w0 : (lg == 1) ? s0 : t0;
          u[3] = (lg == 3) ? w1 : (lg == 1) ? s1 : t1;
          pf[mi] = __builtin_bit_cast(bv8, u);
        }
        __builtin_amdgcn_s_setprio(1);
#pragma unroll
        for (int mi = 0; mi < 2; ++mi)
#pragma unroll
          for (int nO = 0; nO < 4; ++nO)
            Oa[mi][nO] = __builtin_amdgcn_mfma_f32_16x16x32_bf16(vf[nO], pf[mi], Oa[mi][nO], 0, 0, 0);
        __builtin_amdgcn_s_setprio(0);
      }
    }

    __syncthreads();
    cur ^= 1;
  }

#pragma unroll
  for (int mi = 0; mi < 2; ++mi) {
    lsum[mi] += __shfl_xor(lsum[mi], 16);
    lsum[mi] += __shfl_xor(lsum[mi], 32);
  }

#pragma unroll
  for (int mi = 0; mi < 2; ++mi) {
    const float inv = 1.f / lsum[mi];
    const int q = q0 + w * 32 + mi * 16 + lr;
#pragma unroll
    for (int nO = 0; nO < 4; ++nO) {
      sv4 o;
#pragma unroll
      for (int j = 0; j < 4; ++j) o[j] = f2bs(Oa[mi][nO][j] * inv);
      const int c = h * 64 + nO * 16 + lg * 4;
      *(sv4*)(Oc + ((size_t)b * 2048 + q) * 1024 + c) = o;
    }
  }
}

// ---------------- residual + LayerNorm (mean, unbiased std, eps on std) ----------------
template<int MODE>
__global__ __launch_bounds__(256) void k_resnorm(const short* __restrict__ a, const void* __restrict__ res,
                                                 const float* __restrict__ alpha, const float* __restrict__ beta,
                                                 void* __restrict__ out) {
  const int row = blockIdx.x;
  const int t = threadIdx.x;
  const int lane = t & 63, w = t >> 6;
  const size_t base = (size_t)row * 1024;

  const sv4 av = *(const sv4*)(a + base + t * 4);
  float v[4];
  if (MODE == 0) {
    const float4 rv = *(const float4*)((const float*)res + base + t * 4);
    v[0] = bs2f(av[0]) + rv.x; v[1] = bs2f(av[1]) + rv.y;
    v[2] = bs2f(av[2]) + rv.z; v[3] = bs2f(av[3]) + rv.w;
  } else {
    const sv4 rv = *(const sv4*)((const short*)res + base + t * 4);
#pragma unroll
    for (int i = 0; i < 4; ++i) v[i] = bs2f(av[i]) + bs2f(rv[i]);
  }
  float s = v[0] + v[1] + v[2] + v[3];
  float sq = v[0] * v[0] + v[1] * v[1] + v[2] * v[2] + v[3] * v[3];
#pragma unroll
  for (int m = 1; m < 64; m <<= 1) { s += __shfl_xor(s, m); sq += __shfl_xor(sq, m); }
  __shared__ float red[8];
  if (lane == 0) { red[w] = s; red[w + 4] = sq; }
  __syncthreads();
  s = red[0] + red[1] + red[2] + red[3];
  sq = red[4] + red[5] + red[6] + red[7];
  const float mean = s * (1.f / 1024.f);
  const float var = (sq - 1024.f * mean * mean) * (1.f / 1023.f);   // ddof=1
  const float inv = 1.f / (sqrtf(fmaxf(var, 0.f)) + 1e-6f);          // eps added to std
  const float4 al = *(const float4*)(alpha + t * 4);
  const float4 be = *(const float4*)(beta + t * 4);
  float y[4];
  y[0] = al.x * (v[0] - mean) * inv + be.x;
  y[1] = al.y * (v[1] - mean) * inv + be.y;
  y[2] = al.z * (v[2] - mean) * inv + be.z;
  y[3] = al.w * (v[3] - mean) * inv + be.w;
  if (MODE == 0) {
    sv4 o; o[0] = f2bs(y[0]); o[1] = f2bs(y[1]); o[2] = f2bs(y[2]); o[3] = f2bs(y[3]);
    *(sv4*)((short*)out + base + t * 4) = o;
  } else {
    *(float4*)((float*)out + base + t * 4) = make_float4(y[0], y[1], y[2], y[3]);
  }
}

extern "C" void kernel_launch(void* const* d_in, const int* in_sizes, int n_in,
                              void* d_out, int out_size, void* d_ws, size_t ws_size,
                              hipStream_t stream) {
  const float* x   = (const float*)d_in[0];
  const float* Wq  = (const float*)d_in[1];
  const float* bq  = (const float*)d_in[2];
  const float* Wk  = (const float*)d_in[3];
  const float* bk  = (const float*)d_in[4];
  const float* Wv  = (const float*)d_in[5];
  const float* bv  = (const float*)d_in[6];
  const float* Wo  = (const float*)d_in[7];
  const float* bo  = (const float*)d_in[8];
  const float* al1 = (const float*)d_in[9];
  const float* bi1 = (const float*)d_in[10];
  const float* al2 = (const float*)d_in[11];
  const float* bi2 = (const float*)d_in[12];
  const float* W1  = (const float*)d_in[13];
  const float* b1  = (const float*)d_in[14];
  const float* W2  = (const float*)d_in[15];
  const float* b2  = (const float*)d_in[16];

  if (ws_size < (size_t)136 * 1024 * 1024) return;  // need 136MB scratch

  char* ws = (char*)d_ws;
  short* xb  = (short*)(ws);                   // 16MB, dead after QKV
  short* Qb  = (short*)(ws + (16ll << 20));    // 16MB
  short* Kb  = (short*)(ws + (32ll << 20));    // 16MB
  short* Vtb = (short*)(ws + (48ll << 20));    // 16MB
  short* Hb  = (short*)(ws);                   // 64MB: reuses xb+Q+K+Vt after attention
  short* Wqt = (short*)(ws + (64ll << 20));    // [3072][1024] contiguous with Wkt/Wvt
  short* Wkt = (short*)(ws + (66ll << 20));
  short* Wvt = (short*)(ws + (68ll << 20));
  short* Wot = (short*)(ws + (70ll << 20));
  short* W1t = (short*)(ws + (72ll << 20));    // 8MB
  short* W2t = (short*)(ws + (80ll << 20));    // 8MB
  short* Cc  = (short*)(ws + (88ll << 20));    // 16MB
  short* AOb = (short*)(ws + (104ll << 20));   // 16MB, reused for FFb
  short* N1b = (short*)(ws + (120ll << 20));   // 16MB
  short* FFb = (short*)(ws + (104ll << 20));

  // prep: bf16 conversions + weight transposes
  k_cvt<<<8192, 256, 0, stream>>>(x, xb);
  k_transpose<<<dim3(32, 32), 256, 0, stream>>>(Wq, Wqt, 1024, 1024);
  k_transpose<<<dim3(32, 32), 256, 0, stream>>>(Wk, Wkt, 1024, 1024);
  k_transpose<<<dim3(32, 32), 256, 0, stream>>>(Wv, Wvt, 1024, 1024);
  k_transpose<<<dim3(32, 32), 256, 0, stream>>>(Wo, Wot, 1024, 1024);
  k_transpose<<<dim3(128, 32), 256, 0, stream>>>(W1, W1t, 1024, 4096);
  k_transpose<<<dim3(32, 128), 256, 0, stream>>>(W2, W2t, 4096, 1024);

  // fused QKV: 8192x3072 @ K=1024, 128x256 tiles -> grid 64*12 = 768 (3 full CU rounds)
  k_gemm8p<2, 2><<<768, 512, 0, stream>>>(xb, Wqt, bq, bk, bv, Qb, Kb, Vtb, 8192, 3072, 1024, 12);

  // attention -> concat
  k_attn<<<1024, 256, 0, stream>>>(Qb, Kb, Vtb, Cc);

  // output proj: 8192x1024, 128x256 tiles -> grid 64*4 = 256 (1 full round)
  k_gemm8p<0, 2><<<256, 512, 0, stream>>>(Cc, Wot, bo, nullptr, nullptr, AOb, nullptr, nullptr,
                                          8192, 1024, 1024, 4);
  k_resnorm<0><<<8192, 256, 0, stream>>>(AOb, x, al1, bi1, N1b);

  // FFN1: 8192x4096 relu, 256x256 tiles -> grid 32*16 = 512 (2 full rounds)
  k_gemm8p<1, 4><<<512, 512, 0, stream>>>(N1b, W1t, b1, nullptr, nullptr, Hb, nullptr, nullptr,
                                          8192, 4096, 1024, 16);
  // FFN2: 8192x1024 @ K=4096, 128x256 tiles -> grid 256
  k_gemm8p<0, 2><<<256, 512, 0, stream>>>(Hb, W2t, b2, nullptr, nullptr, FFb, nullptr, nullptr,
                                          8192, 1024, 4096, 4);
  k_resnorm<1><<<8192, 256, 0, stream>>>(FFb, N1b, al2, bi2, (float*)d_out);
}

// Round 10
// 449.748 us; speedup vs baseline: 1.1237x; 1.0536x over previous
//
#include <hip/hip_runtime.h>
#include <hip/hip_bf16.h>
#include <stdint.h>

typedef __attribute__((ext_vector_type(8))) short bv8;   // 8 x bf16 (MFMA A/B frag)
typedef __attribute__((ext_vector_type(4))) short sv4;   // 4 x bf16
typedef __attribute__((ext_vector_type(4))) float f4;    // MFMA C/D frag
typedef __attribute__((ext_vector_type(4))) unsigned uv4;

#define LDS_AS __attribute__((address_space(3)))
#define GLB_AS __attribute__((address_space(1)))

#if __has_builtin(__builtin_amdgcn_exp2f)
#define EXP2F(x) __builtin_amdgcn_exp2f(x)
#else
#define EXP2F(x) exp2f(x)
#endif

#define GBAR __builtin_amdgcn_s_barrier()

__device__ __forceinline__ void gload16(const void* g, void* l) {
  __builtin_amdgcn_global_load_lds((GLB_AS void*)(g), (LDS_AS void*)(l), 16, 0, 0);
}

__device__ __forceinline__ short f2bs(float x) {
  return __builtin_bit_cast(short, __float2bfloat16(x));
}
__device__ __forceinline__ float bs2f(short s) {
  unsigned u = ((unsigned)(unsigned short)s) << 16;
  return __builtin_bit_cast(float, u);
}
__device__ __forceinline__ unsigned cvtpk(float lo, float hi) {
  unsigned r;
  asm("v_cvt_pk_bf16_f32 %0, %1, %2" : "=v"(r) : "v"(lo), "v"(hi));
  return r;
}

// ---------------- fused prep: x cvt + all 6 weight transposes in ONE launch ----------------
// blocks [0,8192): cvt x. [8192,9216) Wq, [9216,10240) Wk, [10240,11264) Wv,
// [11264,12288) Wo (all 1024x1024). [12288,16384) W1 (K=1024,N=4096).
// [16384,20480) W2 (K=4096,N=1024).
__global__ __launch_bounds__(256) void k_prep(const float* __restrict__ x, short* __restrict__ xb,
                                              const float* __restrict__ Wq, short* __restrict__ Wqt,
                                              const float* __restrict__ Wk, short* __restrict__ Wkt,
                                              const float* __restrict__ Wv, short* __restrict__ Wvt,
                                              const float* __restrict__ Wo, short* __restrict__ Wot,
                                              const float* __restrict__ W1, short* __restrict__ W1t,
                                              const float* __restrict__ W2, short* __restrict__ W2t) {
  const int bid = blockIdx.x;
  if (bid < 8192) {
    const int i = (bid * 256 + threadIdx.x) * 4;
    const float4 v = *(const float4*)(x + i);
    sv4 o; o[0] = f2bs(v.x); o[1] = f2bs(v.y); o[2] = f2bs(v.z); o[3] = f2bs(v.w);
    *(sv4*)(xb + i) = o;
    return;
  }
  const float* W; short* Wt; int K, N, l;
  if (bid < 12288) {
    l = (bid - 8192) & 1023; K = 1024; N = 1024;
    const int sel = (bid - 8192) >> 10;
    W  = sel == 0 ? Wq  : sel == 1 ? Wk  : sel == 2 ? Wv  : Wo;
    Wt = sel == 0 ? Wqt : sel == 1 ? Wkt : sel == 2 ? Wvt : Wot;
  } else if (bid < 16384) {
    l = bid - 12288; K = 1024; N = 4096; W = W1; Wt = W1t;
  } else {
    l = bid - 16384; K = 4096; N = 1024; W = W2; Wt = W2t;
  }
  const int nb = N >> 5;
  const int n0 = (l % nb) * 32, k0 = (l / nb) * 32;
  __shared__ float tile[32][33];
  const int tx = threadIdx.x & 31, ty = threadIdx.x >> 5;
#pragma unroll
  for (int i = 0; i < 32; i += 8)
    tile[ty + i][tx] = W[(size_t)(k0 + ty + i) * N + n0 + tx];
  __syncthreads();
#pragma unroll
  for (int i = 0; i < 32; i += 8)
    Wt[(size_t)(n0 + ty + i) * K + k0 + tx] = f2bs(tile[tx][ty + i]);
}

// ======== 8-phase GEMM (T2+T3+T4+T5): BMxBN tile, BN=256, BM=MIH*64 ========
// (validated R9; unchanged) EPI: 0 plain bf16, 1 relu bf16, 2 QKV scatter.
template<int EPI, int MIH>
__global__ __launch_bounds__(512) void k_gemm8p(
    const short* __restrict__ A, const short* __restrict__ Bt,
    const float* __restrict__ bias, const float* __restrict__ bias2, const float* __restrict__ bias3,
    short* __restrict__ C, short* __restrict__ D2, short* __restrict__ D3,
    int M, int N, int K, int nbx) {
  constexpr int BM = MIH * 64;
  constexpr int HOFF = (MIH == 4) ? 16384 : 4096;
  __shared__ __align__(16) short SA[2][BM * 64];
  __shared__ __align__(16) short SB[2][256 * 64];

  const int t = threadIdx.x;
  const int lane = t & 63, w = t >> 6;
  const int wr = w >> 2, wc = w & 3;
  const int lr = lane & 15, lg = lane >> 4;
  const int cpx = gridDim.x >> 3;
  const int bid = blockIdx.x;
  const int wid = (bid & 7) * cpx + (bid >> 3);
  const int by = wid / nbx, bx = wid % nbx;
  const int m0 = by * BM, n0 = bx * 256;
  const int nt = K >> 6;
  const int swz = ((t >> 3) & 7) << 4;
  const int rbyte0 = (lg * 16) ^ ((lr & 7) << 4);
  const int rbyte1 = (64 + lg * 16) ^ ((lr & 7) << 4);

  auto ST_A = [&](int k0, int half, int buf) {
#pragma unroll
    for (int i = 0; i < 2; ++i) {
      const int L = t * 16 + i * 8192;
      const int cbs = (L & 127) ^ swz;
      const int grow = (MIH == 4) ? (m0 + i * 128 + half * 64 + (t >> 3))
                                  : (m0 + i * 64 + (t >> 3));
      gload16(A + (size_t)grow * K + k0 + (cbs >> 1),
              (char*)SA[buf] + (MIH == 4 ? half * 16384 : 0) + L);
    }
  };
  auto ST_B = [&](int k0, int half, int buf) {
#pragma unroll
    for (int i = 0; i < 2; ++i) {
      const int L = t * 16 + i * 8192;
      const int rr = (t >> 3) + i * 64;
      const int cbs = (L & 127) ^ swz;
      const int grow = n0 + (rr >> 5) * 64 + half * 32 + (rr & 31);
      gload16(Bt + (size_t)grow * K + k0 + (cbs >> 1),
              (char*)SB[buf] + half * 16384 + L);
    }
  };

  f4 acc[2 * MIH][4] = {};
  bv8 af[MIH][2], bflo[2][2], bfhi[2][2];

  auto LDA = [&](int buf, int half) {
    const char* base = (const char*)SA[buf] + half * HOFF + wr * 8192;
#pragma unroll
    for (int m = 0; m < MIH; ++m) {
      af[m][0] = *(const bv8*)(base + (m * 16 + lr) * 128 + rbyte0);
      af[m][1] = *(const bv8*)(base + (m * 16 + lr) * 128 + rbyte1);
    }
  };
  auto LDB = [&](int buf, int half, bv8 (&bf)[2][2]) {
    const char* base = (const char*)SB[buf] + half * 16384 + wc * 4096;
#pragma unroll
    for (int n = 0; n < 2; ++n) {
      bf[n][0] = *(const bv8*)(base + (n * 16 + lr) * 128 + rbyte0);
      bf[n][1] = *(const bv8*)(base + (n * 16 + lr) * 128 + rbyte1);
    }
  };
  auto MM = [&](bv8 (&bf)[2][2], int mB, int nB) {
    __builtin_amdgcn_s_setprio(1);
#pragma unroll
    for (int kk = 0; kk < 2; ++kk)
#pragma unroll
      for (int m = 0; m < MIH; ++m)
#pragma unroll
        for (int n = 0; n < 2; ++n)
          acc[mB + m][nB + n] = __builtin_amdgcn_mfma_f32_16x16x32_bf16(
              af[m][kk], bf[n][kk], acc[mB + m][nB + n], 0, 0, 0);
    __builtin_amdgcn_s_setprio(0);
  };

  ST_A(0, 0, 0); if (MIH == 4) ST_A(0, 1, 0);
  ST_B(0, 0, 0); ST_B(0, 1, 0);
  ST_A(64, 0, 1);
  ST_B(64, 1, 1);
  if (MIH == 4) { ST_A(64, 1, 1); asm volatile("s_waitcnt vmcnt(6)" ::: "memory"); }
  else          { asm volatile("s_waitcnt vmcnt(4)" ::: "memory"); }
  GBAR;

  const int nIter = nt >> 1;
  for (int it = 0; it < nIter; ++it) {
    const int k1 = (2 * it + 1) << 6;
    const int k2 = (2 * it + 2) << 6, k3 = (2 * it + 3) << 6;
    const bool h2 = (2 * it + 2) < nt, h3 = (2 * it + 3) < nt;

    LDA(0, 0); LDB(0, 0, bflo);
    ST_B(k1, 0, 1);
    GBAR; MM(bflo, 0, 0); GBAR;
    LDB(0, 1, bfhi);
    if (h2 && MIH == 4) ST_A(k2, 0, 0);
    GBAR; MM(bfhi, 0, 2); GBAR;
    LDA(0, 1);
    if (h2) ST_B(k2, 1, 0);
    GBAR; MM(bfhi, MIH, 2); GBAR;
    if (h2) ST_A(k2, (MIH == 4) ? 1 : 0, 0);
    if (h2) {
      if (MIH == 4) asm volatile("s_waitcnt vmcnt(6)" ::: "memory");
      else          asm volatile("s_waitcnt vmcnt(4)" ::: "memory");
    } else {
      asm volatile("s_waitcnt vmcnt(0)" ::: "memory");
    }
    GBAR; MM(bflo, MIH, 0); GBAR;

    LDA(1, 0); LDB(1, 0, bflo);
    if (h2) ST_B(k2, 0, 0);
    GBAR; MM(bflo, 0, 0); GBAR;
    LDB(1, 1, bfhi);
    if (h3 && MIH == 4) ST_A(k3, 0, 1);
    GBAR; MM(bfhi, 0, 2); GBAR;
    LDA(1, 1);
    if (h3) ST_B(k3, 1, 1);
    GBAR; MM(bfhi, MIH, 2); GBAR;
    if (h3) ST_A(k3, (MIH == 4) ? 1 : 0, 1);
    if (h3) {
      if (MIH == 4) asm volatile("s_waitcnt vmcnt(6)" ::: "memory");
      else          asm volatile("s_waitcnt vmcnt(4)" ::: "memory");
    } else {
      asm volatile("s_waitcnt vmcnt(0)" ::: "memory");
    }
    GBAR; MM(bflo, MIH, 0); GBAR;
  }

#pragma unroll
  for (int ni = 0; ni < 4; ++ni) {
    const int c = n0 + wc * 64 + ni * 16 + lr;
    float bvs;
    int sel = 0, h = 0, d = 0;
    if (EPI == 2) {
      sel = c >> 10; const int cc = c & 1023;
      bvs = (sel == 0 ? bias : sel == 1 ? bias2 : bias3)[cc];
      h = cc >> 6; d = cc & 63;
    } else {
      bvs = bias[c];
    }
#pragma unroll
    for (int mi = 0; mi < 2 * MIH; ++mi) {
#pragma unroll
      for (int j = 0; j < 4; ++j) {
        const int r = m0 + wr * (MIH * 32) + mi * 16 + lg * 4 + j;
        float v = acc[mi][ni][j] + bvs;
        if (EPI == 1) v = fmaxf(v, 0.f);
        if (EPI == 2) {
          const int bb = r >> 11, s = r & 2047;
          if (sel == 0)      C [((size_t)(bb * 16 + h) * 2048 + s) * 64 + d] = f2bs(v);
          else if (sel == 1) D2[((size_t)(bb * 16 + h) * 2048 + s) * 64 + d] = f2bs(v);
          else               D3[((size_t)(bb * 16 + h) * 64 + d) * 2048 + s] = f2bs(v);
        } else {
          C[(size_t)r * N + c] = f2bs(v);
        }
      }
    }
  }
}

// ---------------- flash attention: in-reg P + explicit V prefetch (T14) ----------------
// per block = (q-tile 128, bh), 4 waves x 32 q-rows. S^T = mfma(K,Q): q on lane&15,
// k on reg axis -> lane-local fixed-max softmax. P->PV B-frags via cvt_pk + 4-group
// shfl network (validated R6). V frags for half 0 issued BEFORE QK(0) (hidden under
// QK+SM ~700cyc); half 1's V issued before PV(0) (hidden under PV0+QK1+SM1).
// K tile dbuf in LDS (32KB), stage-ahead; single barrier per tile.
__global__ __launch_bounds__(256) void k_attn(const short* __restrict__ Qg, const short* __restrict__ Kg,
                                              const short* __restrict__ Vtg, short* __restrict__ Oc) {
  __shared__ __align__(16) short Ks[2][128 * 64];  // dbuf [s][dk] swizzled, 128B rows

  const int t = threadIdx.x, lane = t & 63, w = t >> 6;
  const int lr = lane & 15, lg = lane >> 4;
  const int bid = blockIdx.x;
  const int wid = (bid & 7) * 128 + (bid >> 3);
  const int q0 = (wid & 15) * 128;
  const int bh = wid >> 4;
  const int b = bh >> 4, h = bh & 15;
  const short* Qp = Qg + (size_t)bh * 2048 * 64;
  const short* Kp = Kg + (size_t)bh * 2048 * 64;
  const short* Vp = Vtg + (size_t)bh * 64 * 2048;

  bv8 qf[2][2];
#pragma unroll
  for (int mi = 0; mi < 2; ++mi)
#pragma unroll
    for (int kk = 0; kk < 2; ++kk)
      qf[mi][kk] = *(const bv8*)(Qp + (size_t)(q0 + w * 32 + mi * 16 + lr) * 64 + kk * 32 + lg * 8);

  f4 Oa[2][4] = {};
  float lsum[2] = {0.f, 0.f};
  const float SC = 0.125f * 1.44269504089f;
  const bool hi = lg >= 2;
  const bool xx = (lg == 1) || (lg == 2);

  // per-half helpers
  auto QKSM = [&](const char* Kb, int hf, bv8 (&pf)[2][2]) {
    f4 Sa[2][4] = {};
#pragma unroll
    for (int kk = 0; kk < 2; ++kk) {
      bv8 kf[4];
#pragma unroll
      for (int nl = 0; nl < 4; ++nl) {
        const int row = (hf * 4 + nl) * 16 + lr;
        const int cb = kk * 64 + lg * 16;
        kf[nl] = *(const bv8*)(Kb + row * 128 + (cb ^ ((row & 7) << 4)));
      }
      __builtin_amdgcn_s_setprio(1);
#pragma unroll
      for (int mi = 0; mi < 2; ++mi)
#pragma unroll
        for (int nl = 0; nl < 4; ++nl)
          Sa[mi][nl] = __builtin_amdgcn_mfma_f32_16x16x32_bf16(kf[nl], qf[mi][kk], Sa[mi][nl], 0, 0, 0);
      __builtin_amdgcn_s_setprio(0);
    }
#pragma unroll
    for (int mi = 0; mi < 2; ++mi) {
      float rs = 0.f;
#pragma unroll
      for (int nl = 0; nl < 4; ++nl)
#pragma unroll
        for (int j = 0; j < 4; ++j) {
          const float p = EXP2F(Sa[mi][nl][j] * SC);
          Sa[mi][nl][j] = p;
          rs += p;
        }
      lsum[mi] += rs;
    }
#pragma unroll
    for (int k2 = 0; k2 < 2; ++k2)
#pragma unroll
      for (int mi = 0; mi < 2; ++mi) {
        const unsigned W0 = cvtpk(Sa[mi][2 * k2][0], Sa[mi][2 * k2][1]);
        const unsigned W1 = cvtpk(Sa[mi][2 * k2][2], Sa[mi][2 * k2][3]);
        const unsigned W2 = cvtpk(Sa[mi][2 * k2 + 1][0], Sa[mi][2 * k2 + 1][1]);
        const unsigned W3 = cvtpk(Sa[mi][2 * k2 + 1][2], Sa[mi][2 * k2 + 1][3]);
        const unsigned w0 = hi ? W2 : W0, w1 = hi ? W3 : W1;
        const unsigned s0 = __shfl_xor(hi ? W0 : W2, 32);
        const unsigned s1 = __shfl_xor(hi ? W1 : W3, 32);
        const unsigned t0 = __shfl_xor(xx ? w0 : s0, 16);
        const unsigned t1 = __shfl_xor(xx ? w1 : s1, 16);
        uv4 u;
        u[0] = (lg == 0) ? w0 : (lg == 2) ? s0 : t0;
        u[1] = (lg == 0) ? w1 : (lg == 2) ? s1 : t1;
        u[2] = (lg == 3) ? w0 : (lg == 1) ? s0 : t0;
        u[3] = (lg == 3) ? w1 : (lg == 1) ? s1 : t1;
        pf[k2][mi] = __builtin_bit_cast(bv8, u);
      }
  };
  auto LOADV = [&](int kt, int hf, bv8 (&vf)[2][4]) {
#pragma unroll
    for (int k2 = 0; k2 < 2; ++k2)
#pragma unroll
      for (int nO = 0; nO < 4; ++nO)
        vf[k2][nO] = *(const bv8*)(Vp + (size_t)(nO * 16 + lr) * 2048 + kt + hf * 64 + k2 * 32 + lg * 8);
  };
  auto PV = [&](bv8 (&vf)[2][4], bv8 (&pf)[2][2]) {
    __builtin_amdgcn_s_setprio(1);
#pragma unroll
    for (int k2 = 0; k2 < 2; ++k2)
#pragma unroll
      for (int mi = 0; mi < 2; ++mi)
#pragma unroll
        for (int nO = 0; nO < 4; ++nO)
          Oa[mi][nO] = __builtin_amdgcn_mfma_f32_16x16x32_bf16(vf[k2][nO], pf[k2][mi], Oa[mi][nO], 0, 0, 0);
    __builtin_amdgcn_s_setprio(0);
  };

#pragma unroll
  for (int i = 0; i < 4; ++i) {
    const int L = t * 16 + i * 4096;
    const int row = L >> 7;
    const int cbs = (L & 127) ^ ((row & 7) << 4);
    gload16(Kp + (size_t)row * 64 + (cbs >> 1), (char*)Ks[0] + L);
  }
  __syncthreads();

  int cur = 0;
  for (int kt = 0; kt < 2048; kt += 128) {
    if (kt + 128 < 2048) {
#pragma unroll
      for (int i = 0; i < 4; ++i) {
        const int L = t * 16 + i * 4096;
        const int row = L >> 7;
        const int cbs = (L & 127) ^ ((row & 7) << 4);
        gload16(Kp + (size_t)(kt + 128 + row) * 64 + (cbs >> 1), (char*)Ks[cur ^ 1] + L);
      }
    }
    const char* Kb = (const char*)Ks[cur];

    bv8 vfA[2][4], vfB[2][4], pfA[2][2], pfB[2][2];
    LOADV(kt, 0, vfA);        // issue V(hf0) early: hidden under QK(0)+SM(0)
    QKSM(Kb, 0, pfA);
    LOADV(kt, 1, vfB);        // issue V(hf1): hidden under PV(0)+QK(1)+SM(1)
    PV(vfA, pfA);
    QKSM(Kb, 1, pfB);
    PV(vfB, pfB);

    __syncthreads();
    cur ^= 1;
  }

#pragma unroll
  for (int mi = 0; mi < 2; ++mi) {
    lsum[mi] += __shfl_xor(lsum[mi], 16);
    lsum[mi] += __shfl_xor(lsum[mi], 32);
  }

#pragma unroll
  for (int mi = 0; mi < 2; ++mi) {
    const float inv = 1.f / lsum[mi];
    const int q = q0 + w * 32 + mi * 16 + lr;
#pragma unroll
    for (int nO = 0; nO < 4; ++nO) {
      sv4 o;
#pragma unroll
      for (int j = 0; j < 4; ++j) o[j] = f2bs(Oa[mi][nO][j] * inv);
      const int c = h * 64 + nO * 16 + lg * 4;
      *(sv4*)(Oc + ((size_t)b * 2048 + q) * 1024 + c) = o;
    }
  }
}

// ---------------- residual + LayerNorm (mean, unbiased std, eps on std) ----------------
template<int MODE>
__global__ __launch_bounds__(256) void k_resnorm(const short* __restrict__ a, const void* __restrict__ res,
                                                 const float* __restrict__ alpha, const float* __restrict__ beta,
                                                 void* __restrict__ out) {
  const int row = blockIdx.x;
  const int t = threadIdx.x;
  const int lane = t & 63, w = t >> 6;
  const size_t base = (size_t)row * 1024;

  const sv4 av = *(const sv4*)(a + base + t * 4);
  float v[4];
  if (MODE == 0) {
    const float4 rv = *(const float4*)((const float*)res + base + t * 4);
    v[0] = bs2f(av[0]) + rv.x; v[1] = bs2f(av[1]) + rv.y;
    v[2] = bs2f(av[2]) + rv.z; v[3] = bs2f(av[3]) + rv.w;
  } else {
    const sv4 rv = *(const sv4*)((const short*)res + base + t * 4);
#pragma unroll
    for (int i = 0; i < 4; ++i) v[i] = bs2f(av[i]) + bs2f(rv[i]);
  }
  float s = v[0] + v[1] + v[2] + v[3];
  float sq = v[0] * v[0] + v[1] * v[1] + v[2] * v[2] + v[3] * v[3];
#pragma unroll
  for (int m = 1; m < 64; m <<= 1) { s += __shfl_xor(s, m); sq += __shfl_xor(sq, m); }
  __shared__ float red[8];
  if (lane == 0) { red[w] = s; red[w + 4] = sq; }
  __syncthreads();
  s = red[0] + red[1] + red[2] + red[3];
  sq = red[4] + red[5] + red[6] + red[7];
  const float mean = s * (1.f / 1024.f);
  const float var = (sq - 1024.f * mean * mean) * (1.f / 1023.f);   // ddof=1
  const float inv = 1.f / (sqrtf(fmaxf(var, 0.f)) + 1e-6f);          // eps added to std
  const float4 al = *(const float4*)(alpha + t * 4);
  const float4 be = *(const float4*)(beta + t * 4);
  float y[4];
  y[0] = al.x * (v[0] - mean) * inv + be.x;
  y[1] = al.y * (v[1] - mean) * inv + be.y;
  y[2] = al.z * (v[2] - mean) * inv + be.z;
  y[3] = al.w * (v[3] - mean) * inv + be.w;
  if (MODE == 0) {
    sv4 o; o[0] = f2bs(y[0]); o[1] = f2bs(y[1]); o[2] = f2bs(y[2]); o[3] = f2bs(y[3]);
    *(sv4*)((short*)out + base + t * 4) = o;
  } else {
    *(float4*)((float*)out + base + t * 4) = make_float4(y[0], y[1], y[2], y[3]);
  }
}

extern "C" void kernel_launch(void* const* d_in, const int* in_sizes, int n_in,
                              void* d_out, int out_size, void* d_ws, size_t ws_size,
                              hipStream_t stream) {
  const float* x   = (const float*)d_in[0];
  const float* Wq  = (const float*)d_in[1];
  const float* bq  = (const float*)d_in[2];
  const float* Wk  = (const float*)d_in[3];
  const float* bk  = (const float*)d_in[4];
  const float* Wv  = (const float*)d_in[5];
  const float* bv  = (const float*)d_in[6];
  const float* Wo  = (const float*)d_in[7];
  const float* bo  = (const float*)d_in[8];
  const float* al1 = (const float*)d_in[9];
  const float* bi1 = (const float*)d_in[10];
  const float* al2 = (const float*)d_in[11];
  const float* bi2 = (const float*)d_in[12];
  const float* W1  = (const float*)d_in[13];
  const float* b1  = (const float*)d_in[14];
  const float* W2  = (const float*)d_in[15];
  const float* b2  = (const float*)d_in[16];

  if (ws_size < (size_t)136 * 1024 * 1024) return;  // need 136MB scratch

  char* ws = (char*)d_ws;
  short* xb  = (short*)(ws);                   // 16MB, dead after QKV
  short* Qb  = (short*)(ws + (16ll << 20));    // 16MB
  short* Kb  = (short*)(ws + (32ll << 20));    // 16MB
  short* Vtb = (short*)(ws + (48ll << 20));    // 16MB
  short* Hb  = (short*)(ws);                   // 64MB: reuses xb+Q+K+Vt after attention
  short* Wqt = (short*)(ws + (64ll << 20));    // [3072][1024] contiguous with Wkt/Wvt
  short* Wkt = (short*)(ws + (66ll << 20));
  short* Wvt = (short*)(ws + (68ll << 20));
  short* Wot = (short*)(ws + (70ll << 20));
  short* W1t = (short*)(ws + (72ll << 20));    // 8MB
  short* W2t = (short*)(ws + (80ll << 20));    // 8MB
  short* Cc  = (short*)(ws + (88ll << 20));    // 16MB
  short* AOb = (short*)(ws + (104ll << 20));   // 16MB, reused for FFb
  short* N1b = (short*)(ws + (120ll << 20));   // 16MB
  short* FFb = (short*)(ws + (104ll << 20));

  // fused prep (1 launch replaces 7)
  k_prep<<<20480, 256, 0, stream>>>(x, xb, Wq, Wqt, Wk, Wkt, Wv, Wvt, Wo, Wot, W1, W1t, W2, W2t);

  // fused QKV: 8192x3072 @ K=1024, 128x256 tiles -> grid 768
  k_gemm8p<2, 2><<<768, 512, 0, stream>>>(xb, Wqt, bq, bk, bv, Qb, Kb, Vtb, 8192, 3072, 1024, 12);

  // attention -> concat
  k_attn<<<1024, 256, 0, stream>>>(Qb, Kb, Vtb, Cc);

  // output proj: 8192x1024, 128x256 tiles -> grid 256
  k_gemm8p<0, 2><<<256, 512, 0, stream>>>(Cc, Wot, bo, nullptr, nullptr, AOb, nullptr, nullptr,
                                          8192, 1024, 1024, 4);
  k_resnorm<0><<<8192, 256, 0, stream>>>(AOb, x, al1, bi1, N1b);

  // FFN1: 8192x4096 relu, 256x256 tiles -> grid 512
  k_gemm8p<1, 4><<<512, 512, 0, stream>>>(N1b, W1t, b1, nullptr, nullptr, Hb, nullptr, nullptr,
                                          8192, 4096, 1024, 16);
  // FFN2: 8192x1024 @ K=4096, 128x256 tiles -> grid 256
  k_gemm8p<0, 2><<<256, 512, 0, stream>>>(Hb, W2t, b2, nullptr, nullptr, FFb, nullptr, nullptr,
                                          8192, 1024, 4096, 4);
  k_resnorm<1><<<8192, 256, 0, stream>>>(FFb, N1b, al2, bi2, (float*)d_out);
}